// Round 1
// baseline (108.792 us; speedup 1.0000x reference)
//
#include <hip/hip_runtime.h>
#include <math.h>

// KF filtered-position windowed loss, collapsed form.
//
// Derivation (see analysis): with HISTORY=1 the positions cancel; loss =
// mean_{b,t in [1,T), d} ( dt*v + kp_t*(z_t - v) - dt*w_t )^2
// where v is the scalar filtered velocity: v <- v + kv_t*(z_t - v), v0 = 0,
// and kp/kv come from a batch-independent scalar Riccati recursion
// (b,c covariance entries; q_pos and p0 provably do not affect the output).
//
// Parallelization: chunk T into NCHUNK chunks of L; the v-recurrence has
// contraction factor alpha = 1-kv ~ 0.73, so a W=64 warm-up from v=0 gives
// the correct chunk-entry state to ~2e-9 relative (tolerance is ~2%).
// Chunks fully in the steady-gain region (t >= 256) use closed-form gains;
// the few transient chunks compute the exact Riccati sequence into LDS.

namespace {
constexpr int   Bn = 512;
constexpr int   Tn = 4096;
constexpr float DTc = 0.005f;
constexpr int   Lc = 64;            // chunk emit length
constexpr int   Wc = 64;            // warm-up length (alpha^64 ~ 2e-9)
constexpr int   NCHUNK = Tn / Lc;   // 64
constexpr int   GB = 4;             // batch groups per chunk (512 / 128)
constexpr int   NTRANSMAX = 256;    // gains exactly tracked for t < 256
constexpr float INVC = 1.0f / (512.0f * 4095.0f * 2.0f);
}

__global__ __launch_bounds__(256) void kf_loss_kernel(
    const float* __restrict__ pred,
    const float* __restrict__ targ,
    const float* __restrict__ q_vel,
    const float* __restrict__ r_vel,
    float* __restrict__ out)
{
  const int tid = threadIdx.x;
  const int d  = tid & 1;           // dimension (x/y)
  const int bl = tid >> 1;          // 0..127 batch within group
  const int c  = blockIdx.x >> 2;   // chunk id
  const int g  = blockIdx.x & (GB - 1);
  const int b  = g * 128 + bl;

  const float qv = q_vel[0];
  const float r  = r_vel[0];

  const int t0 = c * Lc;
  const float* zp = pred + (size_t)b * (Tn * 2) + d;
  const float* wp = targ + (size_t)b * (Tn * 2) + d;

  float acc = 0.0f;

  __shared__ float skp[NTRANSMAX];
  __shared__ float skv[NTRANSMAX];

  if (t0 >= NTRANSMAX) {
    // ---- steady-state gains, closed form (fixed point of the Riccati map)
    // cp* = u solves u^2 - qv*u - qv*r = 0
    float u   = 0.5f * (qv + sqrtf(fmaf(qv, qv, 4.0f * qv * r)));
    float s   = u + r;
    float inv = 1.0f / s;
    float kv  = u * inv;
    float cst = u - qv;                 // c*
    float bst = (DTc * cst * r) / u;    // b*
    float kp  = (bst + DTc * cst) * inv;

    float v = 0.0f;
    int t = t0 - Wc;
    #pragma unroll 16
    for (int i = 0; i < Wc; ++i, ++t) {
      float z = zp[2 * t];
      v = fmaf(kv, z - v, v);
    }
    #pragma unroll 16
    for (int i = 0; i < Lc; ++i, ++t) {
      float z = zp[2 * t];
      float w = wp[2 * t];
      float innov = z - v;
      float e = fmaf(kp, innov, DTc * v);   // pos increment
      e = fmaf(-DTc, w, e);                 // minus gt increment
      acc = fmaf(e, e, acc);
      v = fmaf(kv, innov, v);
    }
  } else {
    // ---- transient chunks: thread 0 runs the exact Riccati recursion
    if (tid == 0) {
      float bcov = 0.0f, ccov = 1.0f;       // P0 = I -> b=0, c=1
      const int nk = t0 + Lc;               // <= 256
      for (int t = 0; t < nk; ++t) {
        float bp = fmaf(DTc, ccov, bcov);
        float cp = ccov + qv;
        float sden = cp + r;
        float inv = __builtin_amdgcn_rcpf(sden);
        float kp = bp * inv;
        float kv = cp * inv;
        skp[t] = kp;
        skv[t] = kv;
        bcov = fmaf(-kp, cp, bp);
        ccov = fmaf(-kv, cp, cp);
      }
    }
    __syncthreads();

    float v = 0.0f;
    int t = t0 - Wc; if (t < 0) t = 0;
    for (; t < t0; ++t) {
      float z = zp[2 * t];
      v = fmaf(skv[t], z - v, v);
    }
    for (; t < t0 + Lc; ++t) {
      float z = zp[2 * t];
      float innov = z - v;
      if (t > 0) {                          // loss terms only for t >= 1
        float w = wp[2 * t];
        float e = fmaf(skp[t], innov, DTc * v);
        e = fmaf(-DTc, w, e);
        acc = fmaf(e, e, acc);
      }
      v = fmaf(skv[t], innov, v);
    }
  }

  // ---- block reduction, then one scaled atomic per block
  #pragma unroll
  for (int off = 32; off > 0; off >>= 1)
    acc += __shfl_down(acc, off);
  __shared__ float wpart[4];
  const int lane = tid & 63, wid = tid >> 6;
  if (lane == 0) wpart[wid] = acc;
  __syncthreads();
  if (tid == 0) {
    float s = (wpart[0] + wpart[1]) + (wpart[2] + wpart[3]);
    atomicAdd(out, s * INVC);
  }
}

extern "C" void kernel_launch(void* const* d_in, const int* in_sizes, int n_in,
                              void* d_out, int out_size, void* d_ws, size_t ws_size,
                              hipStream_t stream) {
  // inputs: 0 pred_vel (B,T,2) f32, 1 targ_vel (B,T,2) f32,
  //         2 q_pos (unused), 3 q_vel, 4 r_vel, 5 p0 (unused)
  const float* pred = (const float*)d_in[0];
  const float* targ = (const float*)d_in[1];
  const float* qv   = (const float*)d_in[3];
  const float* rv   = (const float*)d_in[4];
  float* out = (float*)d_out;

  hipMemsetAsync(out, 0, sizeof(float), stream);  // d_out is poisoned 0xAA

  dim3 grid(NCHUNK * GB);
  dim3 block(256);
  kf_loss_kernel<<<grid, block, 0, stream>>>(pred, targ, qv, rv, out);
}

// Round 2
// 90.054 us; speedup vs baseline: 1.2081x; 1.2081x over previous
//
#include <hip/hip_runtime.h>
#include <math.h>

// KF filtered-position windowed loss, collapsed form (see round-1 derivation).
// loss = mean_{b, t in [1,T), d} ( dt*v + kp_t*(z_t - v) - dt*w_t )^2,
// v <- v + kv_t*(z_t - v), v0 = 0; gains from a batch-independent scalar
// Riccati recursion (q_pos and p0 provably cancel).
//
// Round 2: Lc=16/W=12 chunking (state contraction alpha~0.73 => alpha^12
// ~2e-2 attenuation on an O(1e-5)-coefficient term => ~1e-8 loss error,
// threshold 7.7e-7). Gains are fp32-converged by t~48 (covariance contraction
// ~0.53/step), so only chunks with t0<64 need the exact gain sequence.
// Each thread handles BOTH dims of one (b, chunk): float4 loads (2 timesteps
// x 2 dims), two independent FMA chains. 512 blocks x 256 thr = 2 waves/SIMD.

namespace {
constexpr int   Tn = 4096;
constexpr float DTc = 0.005f;
constexpr int   Lc = 16;            // chunk emit length
constexpr int   Wc = 12;            // warm-up length
constexpr int   NCHUNK = Tn / Lc;   // 256
constexpr int   NTRANS_C = 4;       // chunks with t0 < 64 use exact gains
constexpr int   GAINS_N = NTRANS_C * Lc;  // 64
constexpr float INVC = 1.0f / (512.0f * 4095.0f * 2.0f);
}

__global__ __launch_bounds__(256) void kf_loss_kernel(
    const float* __restrict__ pred,
    const float* __restrict__ targ,
    const float* __restrict__ q_vel,
    const float* __restrict__ r_vel,
    float* __restrict__ out)
{
  const int b = ((blockIdx.x & 1) << 8) + threadIdx.x;  // 0..511
  const int c = blockIdx.x >> 1;                        // 0..255
  const int t0 = c * Lc;

  const float qv = q_vel[0];
  const float r  = r_vel[0];

  const float4* z4 = (const float4*)(pred + (size_t)b * (Tn * 2));
  const float4* w4 = (const float4*)(targ + (size_t)b * (Tn * 2));

  float acc = 0.0f;
  __shared__ float skp[GAINS_N];
  __shared__ float skv[GAINS_N];

  if (c >= NTRANS_C) {
    // ---- steady-state gains, closed form (fixed point of the Riccati map)
    float u   = 0.5f * (qv + sqrtf(fmaf(qv, qv, 4.0f * qv * r)));
    float s   = u + r;
    float inv = 1.0f / s;
    float kv  = u * inv;
    float cst = u - qv;
    float bst = (DTc * cst * r) / u;
    float kp  = (bst + DTc * cst) * inv;

    float vx = 0.0f, vy = 0.0f;
    int j = (t0 - Wc) >> 1;          // float4 index = timestep/2
    #pragma unroll
    for (int i = 0; i < Wc / 2; ++i, ++j) {
      float4 z = z4[j];
      vx = fmaf(kv, z.x - vx, vx);  vy = fmaf(kv, z.y - vy, vy);
      vx = fmaf(kv, z.z - vx, vx);  vy = fmaf(kv, z.w - vy, vy);
    }
    #pragma unroll
    for (int i = 0; i < Lc / 2; ++i, ++j) {
      float4 z = z4[j];
      float4 w = w4[j];
      float ix = z.x - vx, iy = z.y - vy;
      float ex = fmaf(kp, ix, DTc * (vx - w.x));
      float ey = fmaf(kp, iy, DTc * (vy - w.y));
      acc = fmaf(ex, ex, acc);  acc = fmaf(ey, ey, acc);
      vx = fmaf(kv, ix, vx);    vy = fmaf(kv, iy, vy);
      ix = z.z - vx;            iy = z.w - vy;
      ex = fmaf(kp, ix, DTc * (vx - w.z));
      ey = fmaf(kp, iy, DTc * (vy - w.w));
      acc = fmaf(ex, ex, acc);  acc = fmaf(ey, ey, acc);
      vx = fmaf(kv, ix, vx);    vy = fmaf(kv, iy, vy);
    }
  } else {
    // ---- transient chunks (t0 < 64): exact Riccati gain sequence in LDS
    if (threadIdx.x == 0) {
      float bcov = 0.0f, ccov = 1.0f;   // P0 = I -> b=0, c=1
      for (int t = 0; t < GAINS_N; ++t) {
        float bp = fmaf(DTc, ccov, bcov);
        float cp = ccov + qv;
        float inv = 1.0f / (cp + r);
        float kp = bp * inv;
        float kv = cp * inv;
        skp[t] = kp;  skv[t] = kv;
        bcov = fmaf(-kp, cp, bp);
        ccov = fmaf(-kv, cp, cp);
      }
    }
    __syncthreads();

    const float2* z2 = (const float2*)z4;
    const float2* w2 = (const float2*)w4;
    float vx = 0.0f, vy = 0.0f;
    int t = t0 - Wc;  if (t < 0) t = 0;
    for (; t < t0; ++t) {
      float2 z = z2[t];
      float kvt = skv[t];
      vx = fmaf(kvt, z.x - vx, vx);  vy = fmaf(kvt, z.y - vy, vy);
    }
    for (; t < t0 + Lc; ++t) {
      float2 z = z2[t];
      float ix = z.x - vx, iy = z.y - vy;
      if (t > 0) {
        float2 w = w2[t];
        float kpt = skp[t];
        float ex = fmaf(kpt, ix, DTc * (vx - w.x));
        float ey = fmaf(kpt, iy, DTc * (vy - w.y));
        acc = fmaf(ex, ex, acc);  acc = fmaf(ey, ey, acc);
      }
      float kvt = skv[t];
      vx = fmaf(kvt, ix, vx);  vy = fmaf(kvt, iy, vy);
    }
  }

  // ---- block reduction (4 waves), one scaled atomic per block
  #pragma unroll
  for (int off = 32; off > 0; off >>= 1)
    acc += __shfl_down(acc, off);
  __shared__ float wpart[4];
  const int lane = threadIdx.x & 63, wid = threadIdx.x >> 6;
  if (lane == 0) wpart[wid] = acc;
  __syncthreads();
  if (threadIdx.x == 0) {
    float s = (wpart[0] + wpart[1]) + (wpart[2] + wpart[3]);
    atomicAdd(out, s * INVC);
  }
}

extern "C" void kernel_launch(void* const* d_in, const int* in_sizes, int n_in,
                              void* d_out, int out_size, void* d_ws, size_t ws_size,
                              hipStream_t stream) {
  // inputs: 0 pred_vel (B,T,2) f32, 1 targ_vel (B,T,2) f32,
  //         2 q_pos (unused), 3 q_vel, 4 r_vel, 5 p0 (unused)
  const float* pred = (const float*)d_in[0];
  const float* targ = (const float*)d_in[1];
  const float* qv   = (const float*)d_in[3];
  const float* rv   = (const float*)d_in[4];
  float* out = (float*)d_out;

  hipMemsetAsync(out, 0, sizeof(float), stream);  // d_out is poisoned 0xAA

  dim3 grid(NCHUNK * 2);   // 512 blocks: (chunk, batch-half)
  dim3 block(256);
  kf_loss_kernel<<<grid, block, 0, stream>>>(pred, targ, qv, rv, out);
}